// Round 1
// baseline (255.615 us; speedup 1.0000x reference)
//
#include <hip/hip_runtime.h>

// Alias-free activation: up×2 (K=12 kaiser-sinc) -> lrelu(0.1) -> down×2.
// x: (8,128,32768) fp32; filters: 12 fp32 each; out: (8,128,32768) fp32.
//
// Derived direct form (verified against reference index arithmetic):
//   up[2t]   = 2 * sum_j fu[2j]   * xc[t-3+j],  j=0..5
//   up[2t+1] = 2 * sum_j fu[2j+1] * xc[t-2+j],  j=0..5
//   act[n]   = lrelu(up[n])
//   out[t]   = sum_k fd[k] * act[clamp(2t+k-5, 0, 2L-1)], k=0..11
// where xc = edge-clamped x (reference pad=5 edge-pad; clamp equivalent for
// all indices actually used).

#define LROW   32768
#define UP_LEN (2 * LROW)
#define OPT    8
#define BLOCK  256
#define TILE   (OPT * BLOCK)   // 2048 outputs per block
#define NX     (TILE + 16)     // 2064 staged x floats: x[t0-8 .. t0+TILE+7]
#define KS     12
#define SLOPE  0.1f

__global__ __launch_bounds__(BLOCK) void aa_act_kernel(
    const float* __restrict__ x,
    const float* __restrict__ upf,
    const float* __restrict__ dnf,
    float* __restrict__ out)
{
    __shared__ float sx[NX];

    const int tid = threadIdx.x;
    const int t0  = blockIdx.x * TILE;
    const size_t row = blockIdx.y;
    const float* __restrict__ xrow = x + row * (size_t)LROW;
    float* __restrict__ orow       = out + row * (size_t)LROW;

    // Filters: uniform address + constant index -> scalar loads. Fold the
    // reference's `r *` (=2) factor into fu.
    float fu[KS], fd[KS];
#pragma unroll
    for (int k = 0; k < KS; ++k) {
        fu[k] = 2.0f * upf[k];
        fd[k] = dnf[k];
    }

    // ---- Stage x tile (with halo) into LDS ----
    const int  base_g   = t0 - 8;                       // multiple of 8 -> 16B aligned
    const bool interior = (base_g >= 0) && (base_g + NX <= LROW);

    if (interior) {
        const float4* __restrict__ src = reinterpret_cast<const float4*>(xrow + base_g);
        float4* dst = reinterpret_cast<float4*>(sx);
        for (int i = tid; i < NX / 4; i += BLOCK) dst[i] = src[i];
    } else {
        for (int i = tid; i < NX; i += BLOCK) {
            int g = base_g + i;
            g = g < 0 ? 0 : (g >= LROW ? LROW - 1 : g);
            sx[i] = xrow[g];
        }
    }
    __syncthreads();

    // ---- Per-thread x window: xv[m] = xc[t-8+m], m in [0,24) ----
    // Local float base = 8*tid (4-float aligned) -> 6x ds_read_b128.
    const int t = t0 + OPT * tid;
    float xv[24];
    {
        const float4* sx4 = reinterpret_cast<const float4*>(sx);
        const int p = 2 * tid;
#pragma unroll
        for (int q = 0; q < 6; ++q) {
            float4 w = sx4[p + q];
            xv[4*q+0] = w.x; xv[4*q+1] = w.y; xv[4*q+2] = w.z; xv[4*q+3] = w.w;
        }
    }

    // ---- 26 act values in registers: a[e] = act(2t-5+e), e in [0,26) ----
    float a[26];
#pragma unroll
    for (int d = -2; d <= 10; ++d) {      // even up samples: n = 2(t+d), e = 2d+5
        float v = 0.0f;
#pragma unroll
        for (int j = 0; j < 6; ++j) v = fmaf(fu[2*j], xv[d + 5 + j], v);
        a[2*d + 5] = v >= 0.0f ? v : SLOPE * v;
    }
#pragma unroll
    for (int d = -3; d <= 9; ++d) {       // odd up samples: n = 2(t+d)+1, e = 2d+6
        float v = 0.0f;
#pragma unroll
        for (int j = 0; j < 6; ++j) v = fmaf(fu[2*j + 1], xv[d + 6 + j], v);
        a[2*d + 6] = v >= 0.0f ? v : SLOPE * v;
    }

    // ---- Edge replication instead of runtime-clamped indexing (keeps a[] in
    // registers; only thread t==0 and t==LROW-OPT ever need the clamp) ----
    if (t == 0) {
        a[4] = a[5]; a[3] = a[5]; a[2] = a[5]; a[1] = a[5]; a[0] = a[5];
    }
    if (t == LROW - OPT) {
        a[21] = a[20]; a[22] = a[20]; a[23] = a[20]; a[24] = a[20]; a[25] = a[20];
    }

    // ---- Downsample: out[t+m] = sum_k fd[k] * a[2m+k] ----
    float o[OPT];
#pragma unroll
    for (int m = 0; m < OPT; ++m) {
        float acc = 0.0f;
#pragma unroll
        for (int k = 0; k < KS; ++k) acc = fmaf(fd[k], a[2*m + k], acc);
        o[m] = acc;
    }

    float4* po = reinterpret_cast<float4*>(orow + t);   // t % 8 == 0 -> aligned
    po[0] = make_float4(o[0], o[1], o[2], o[3]);
    po[1] = make_float4(o[4], o[5], o[6], o[7]);
}

extern "C" void kernel_launch(void* const* d_in, const int* in_sizes, int n_in,
                              void* d_out, int out_size, void* d_ws, size_t ws_size,
                              hipStream_t stream) {
    const float* x   = (const float*)d_in[0];
    const float* upf = (const float*)d_in[1];
    const float* dnf = (const float*)d_in[2];
    float* out = (float*)d_out;

    const int rows = in_sizes[0] / LROW;          // 8*128 = 1024
    dim3 grid(LROW / TILE, rows);                  // (16, 1024)
    aa_act_kernel<<<grid, dim3(BLOCK), 0, stream>>>(x, upf, dnf, out);
}

// Round 2
// 231.791 us; speedup vs baseline: 1.1028x; 1.1028x over previous
//
#include <hip/hip_runtime.h>

// Alias-free activation: up×2 (K=12 kaiser-sinc) -> lrelu(0.1) -> down×2.
// x: (8,128,32768) fp32; filters: 12 fp32 each; out: (8,128,32768) fp32.
//
// Derived direct form (verified vs reference in R0, absmax 1.6e-2):
//   up[2t]   = 2 * sum_j fu[2j]   * xc[t-3+j],  j=0..5
//   up[2t+1] = 2 * sum_j fu[2j+1] * xc[t-2+j],  j=0..5
//   act[n]   = lrelu(up[n])
//   out[t]   = sum_k fd[k] * act[clamp(2t+k-5, 0, 2L-1)], k=0..11
// where xc = edge-clamped x.
//
// R1 change: no LDS (R0 had 1.94e7 bank-conflict cycles = ~31% of runtime
// from stride-32B ds_read_b128, plus a sync round-trip). Each thread loads
// its 24-float window directly via 6 float4 global loads; the 3x overlap
// between neighboring lanes is served by L1/L2, HBM lines still fetched once.

#define LROW   32768
#define OPT    8
#define BLOCK  256
#define TILE   (OPT * BLOCK)   // 2048 outputs per block
#define KS     12
#define SLOPE  0.1f

__global__ __launch_bounds__(BLOCK) void aa_act_kernel(
    const float* __restrict__ x,
    const float* __restrict__ upf,
    const float* __restrict__ dnf,
    float* __restrict__ out)
{
    const int tid = threadIdx.x;
    const int t   = blockIdx.x * TILE + OPT * tid;     // first output of this thread
    const size_t row = blockIdx.y;
    const float* __restrict__ xrow = x + row * (size_t)LROW;
    float* __restrict__ orow       = out + row * (size_t)LROW;

    // Wave-uniform filter values -> SGPRs. Fold the reference's `r *` (=2)
    // factor into fu.
    float fu[KS], fd[KS];
#pragma unroll
    for (int k = 0; k < KS; ++k) {
        fu[k] = 2.0f * upf[k];
        fd[k] = dnf[k];
    }

    // ---- Per-thread x window: xv[m] = xc[t-8+m], m in [0,24) ----
    const int base_g = t - 8;                           // multiple of 8 -> 16B aligned
    float xv[24];
    if (base_g >= 0 && base_g + 24 <= LROW) {
        const float4* __restrict__ src = reinterpret_cast<const float4*>(xrow + base_g);
#pragma unroll
        for (int q = 0; q < 6; ++q) {
            float4 w = src[q];
            xv[4*q+0] = w.x; xv[4*q+1] = w.y; xv[4*q+2] = w.z; xv[4*q+3] = w.w;
        }
    } else {
        // Only the first/last thread of each row takes this path.
#pragma unroll
        for (int m = 0; m < 24; ++m) {
            int g = base_g + m;
            g = g < 0 ? 0 : (g >= LROW ? LROW - 1 : g);
            xv[m] = xrow[g];
        }
    }

    // ---- 26 act values in registers: a[e] = act(2t-5+e), e in [0,26) ----
    float a[26];
#pragma unroll
    for (int d = -2; d <= 10; ++d) {      // even up samples: n = 2(t+d), e = 2d+5
        float v = 0.0f;
#pragma unroll
        for (int j = 0; j < 6; ++j) v = fmaf(fu[2*j], xv[d + 5 + j], v);
        a[2*d + 5] = v >= 0.0f ? v : SLOPE * v;
    }
#pragma unroll
    for (int d = -3; d <= 9; ++d) {       // odd up samples: n = 2(t+d)+1, e = 2d+6
        float v = 0.0f;
#pragma unroll
        for (int j = 0; j < 6; ++j) v = fmaf(fu[2*j + 1], xv[d + 6 + j], v);
        a[2*d + 6] = v >= 0.0f ? v : SLOPE * v;
    }

    // ---- Edge replication (reference edge-pads act before the down-conv).
    // Only threads t==0 and t==LROW-OPT need it.
    if (t == 0) {
        a[4] = a[5]; a[3] = a[5]; a[2] = a[5]; a[1] = a[5]; a[0] = a[5];
    }
    if (t == LROW - OPT) {
        a[21] = a[20]; a[22] = a[20]; a[23] = a[20]; a[24] = a[20]; a[25] = a[20];
    }

    // ---- Downsample: out[t+m] = sum_k fd[k] * a[2m+k] ----
    float o[OPT];
#pragma unroll
    for (int m = 0; m < OPT; ++m) {
        float acc = 0.0f;
#pragma unroll
        for (int k = 0; k < KS; ++k) acc = fmaf(fd[k], a[2*m + k], acc);
        o[m] = acc;
    }

    float4* po = reinterpret_cast<float4*>(orow + t);   // t % 8 == 0 -> aligned
    po[0] = make_float4(o[0], o[1], o[2], o[3]);
    po[1] = make_float4(o[4], o[5], o[6], o[7]);
}

extern "C" void kernel_launch(void* const* d_in, const int* in_sizes, int n_in,
                              void* d_out, int out_size, void* d_ws, size_t ws_size,
                              hipStream_t stream) {
    const float* x   = (const float*)d_in[0];
    const float* upf = (const float*)d_in[1];
    const float* dnf = (const float*)d_in[2];
    float* out = (float*)d_out;

    const int rows = in_sizes[0] / LROW;          // 8*128 = 1024
    dim3 grid(LROW / TILE, rows);                  // (16, 1024)
    aa_act_kernel<<<grid, dim3(BLOCK), 0, stream>>>(x, upf, dnf, out);
}